// Round 3
// baseline (569.285 us; speedup 1.0000x reference)
//
#include <hip/hip_runtime.h>
#include <hip/hip_bf16.h>

typedef __attribute__((ext_vector_type(8))) short bf16x8;   // 8 bf16 (conv)
typedef __attribute__((ext_vector_type(4))) float f32x4;
typedef __attribute__((ext_vector_type(8))) _Float16 f16x8; // MFMA f16 A/B frag
typedef __attribute__((ext_vector_type(16))) float f32x16;  // 32x32 MFMA C/D
typedef __hip_bfloat16 bf16;
typedef unsigned short u16;

#define NB 8
#define NE 256
#define NN 4096
#define SD 64

__device__ __forceinline__ u16 f2b_bits(float x) {
  bf16 h = __float2bfloat16(x);
  return *reinterpret_cast<u16*>(&h);
}
__device__ __forceinline__ f32x16 z16() {
  f32x16 v;
#pragma unroll
  for (int i = 0; i < 16; ++i) v[i] = 0.f;
  return v;
}
__device__ __forceinline__ void gload_lds16(const void* g, void* l) {
  __builtin_amdgcn_global_load_lds((const __attribute__((address_space(1))) void*)g,
                                   (__attribute__((address_space(3))) void*)l, 16, 0, 0);
}

// ---------------- split f32 -> bf16 hi/lo (conv inputs) ----------------
__global__ __launch_bounds__(256) void k_split(const float* __restrict__ x,
                                               u16* __restrict__ hi, u16* __restrict__ lo, int n4) {
  int i = blockIdx.x * 256 + threadIdx.x;
  if (i >= n4) return;
  float4 v = reinterpret_cast<const float4*>(x)[i];
  float f[4] = {v.x, v.y, v.z, v.w};
  u16 hh[4], ll[4];
#pragma unroll
  for (int j = 0; j < 4; ++j) {
    bf16 hb = __float2bfloat16(f[j]);
    float hf = __bfloat162float(hb);
    hh[j] = *reinterpret_cast<u16*>(&hb);
    ll[j] = f2b_bits(f[j] - hf);
  }
  reinterpret_cast<ushort4*>(hi)[i] = make_ushort4(hh[0], hh[1], hh[2], hh[3]);
  reinterpret_cast<ushort4*>(lo)[i] = make_ushort4(ll[0], ll[1], ll[2], ll[3]);
}

// ------- split + transpose conv weights: w[t][ei][eo] -> whT[t][eo][ei] -------
__global__ __launch_bounds__(256) void k_wsplit(const float* __restrict__ w,
                                                u16* __restrict__ whT, u16* __restrict__ wlT) {
  int i = blockIdx.x * 256 + threadIdx.x;
  int t = i >> 16;
  int r = i & 65535;
  int ei = r >> 8, eo = r & 255;
  float x = w[i];
  bf16 hb = __float2bfloat16(x);
  float hf = __bfloat162float(hb);
  int o = (t << 16) + (eo << 8) + ei;
  whT[o] = *reinterpret_cast<u16*>(&hb);
  wlT[o] = f2b_bits(x - hf);
}

// ---------------- conv 3x3 implicit GEMM, split-bf16; epilogue -> f16 hi/lo ----------------
__global__ __launch_bounds__(256) void k_conv(const u16* __restrict__ inh, const u16* __restrict__ inl,
                                              const u16* __restrict__ whT, const u16* __restrict__ wlT,
                                              const float* __restrict__ bias,
                                              u16* __restrict__ x1h, u16* __restrict__ x1l) {
  __shared__ u16 Ah[128][72], Al[128][72];
  __shared__ u16 Bh[128][72], Bl[128][72];
  int b = blockIdx.x >> 6;
  int rem = blockIdx.x & 63;
  int mt = rem >> 1, et = rem & 1;
  int h0 = mt << 1;
  int tid = threadIdx.x;
  int wid = tid >> 6, lane = tid & 63;
  int wr = wid >> 1, wc = wid & 1;
  int r = lane & 15, g = lane >> 4;
  f32x4 acc[4][4];
#pragma unroll
  for (int i = 0; i < 4; ++i)
#pragma unroll
    for (int j = 0; j < 4; ++j) acc[i][j] = (f32x4){0.f, 0.f, 0.f, 0.f};
  const long ibase = (long)b * NN * NE;

#pragma unroll 1
  for (int t = 0; t < 9; ++t) {
    int dy = t / 3 - 1, dx = t % 3 - 1;
#pragma unroll 1
    for (int kc = 0; kc < 4; ++kc) {
      __syncthreads();
      for (int c = tid; c < 1024; c += 256) {
        int pix = c >> 3, c8 = c & 7;
        int ww = pix & 63, hh = h0 + (pix >> 6);
        int sh = hh + dy, sw = ww + dx;
        float4 vh = make_float4(0.f, 0.f, 0.f, 0.f), vl = vh;
        if ((unsigned)sh < 64u && (unsigned)sw < 64u) {
          long off = ibase + ((long)sh * 64 + sw) * NE + kc * 64 + c8 * 8;
          vh = *reinterpret_cast<const float4*>(inh + off);
          vl = *reinterpret_cast<const float4*>(inl + off);
        }
        *reinterpret_cast<float4*>(&Ah[pix][c8 * 8]) = vh;
        *reinterpret_cast<float4*>(&Al[pix][c8 * 8]) = vl;
      }
      for (int c = tid; c < 1024; c += 256) {
        int eo = c >> 3, c8 = c & 7;
        long off = ((long)t << 16) + (et * 128 + eo) * 256 + kc * 64 + c8 * 8;
        *reinterpret_cast<float4*>(&Bh[eo][c8 * 8]) = *reinterpret_cast<const float4*>(whT + off);
        *reinterpret_cast<float4*>(&Bl[eo][c8 * 8]) = *reinterpret_cast<const float4*>(wlT + off);
      }
      __syncthreads();
#pragma unroll
      for (int ks = 0; ks < 2; ++ks) {
        int c8 = ks * 4 + g;
        bf16x8 ah[4], al[4], bh[4], bl[4];
#pragma unroll
        for (int mi = 0; mi < 4; ++mi) {
          int row = wr * 64 + mi * 16 + r;
          ah[mi] = *reinterpret_cast<const bf16x8*>(&Ah[row][c8 * 8]);
          al[mi] = *reinterpret_cast<const bf16x8*>(&Al[row][c8 * 8]);
        }
#pragma unroll
        for (int ni = 0; ni < 4; ++ni) {
          int col = wc * 64 + ni * 16 + r;
          bh[ni] = *reinterpret_cast<const bf16x8*>(&Bh[col][c8 * 8]);
          bl[ni] = *reinterpret_cast<const bf16x8*>(&Bl[col][c8 * 8]);
        }
#pragma unroll
        for (int mi = 0; mi < 4; ++mi)
#pragma unroll
          for (int ni = 0; ni < 4; ++ni) {
            acc[mi][ni] = __builtin_amdgcn_mfma_f32_16x16x32_bf16(ah[mi], bh[ni], acc[mi][ni], 0, 0, 0);
            acc[mi][ni] = __builtin_amdgcn_mfma_f32_16x16x32_bf16(ah[mi], bl[ni], acc[mi][ni], 0, 0, 0);
            acc[mi][ni] = __builtin_amdgcn_mfma_f32_16x16x32_bf16(al[mi], bh[ni], acc[mi][ni], 0, 0, 0);
          }
      }
    }
  }
  // epilogue: +bias, split to f16 hi/lo
#pragma unroll
  for (int mi = 0; mi < 4; ++mi)
#pragma unroll
    for (int ni = 0; ni < 4; ++ni) {
      int eo = et * 128 + wc * 64 + ni * 16 + r;
      float bz = bias[eo];
#pragma unroll
      for (int i = 0; i < 4; ++i) {
        int pix = mt * 128 + wr * 64 + mi * 16 + g * 4 + i;
        float v = acc[mi][ni][i] + bz;
        _Float16 hf = (_Float16)v;
        long o = ibase + (long)pix * NE + eo;
        x1h[o] = __builtin_bit_cast(u16, hf);
        x1l[o] = __builtin_bit_cast(u16, (_Float16)(v - (float)hf));
      }
    }
}

// ---------------- transpose x1h[b][m][e] -> x1T[b][e][m] (f16 bits, u16-agnostic) ----------------
__global__ __launch_bounds__(256) void k_trans(const u16* __restrict__ x1h, u16* __restrict__ x1T) {
  __shared__ u16 T[64][72];
  int bid = blockIdx.x;
  int b = bid >> 8, rem = bid & 255;
  int mt = rem >> 2, et = rem & 3;
  int tid = threadIdx.x;
  for (int c = tid; c < 512; c += 256) {
    int rr = c >> 3, c8 = c & 7;
    *reinterpret_cast<float4*>(&T[rr][c8 * 8]) =
        *reinterpret_cast<const float4*>(x1h + ((long)b * NN + mt * 64 + rr) * NE + et * 64 + c8 * 8);
  }
  __syncthreads();
  for (int c = tid; c < 512; c += 256) {
    int er = c >> 3, m8 = c & 7;
    union { u16 u[8]; float4 v; } p;
#pragma unroll
    for (int j = 0; j < 8; ++j) p.u[j] = T[m8 * 8 + j][er];
    *reinterpret_cast<float4*>(x1T + ((long)b * NE + et * 64 + er) * NN + mt * 64 + m8 * 8) = p.v;
  }
}

// ---------------- fused flash attention, fp16, 32x32 MFMA ----------------
// block 256 = 4 waves; wave owns 32 q-rows; grid 256 (8b x 32mt, XCD-swizzled).
// KVBLK=32 double-buffered; LDS/buf: Kh[32][512B] @0, Kl @16K, Vt[256][128B] @32K; 2 bufs = 128KB.
// Staged via global_load_lds with source-XOR swizzle; reads use byte^((row&7)<<4).
__device__ __forceinline__ void stage_tile(const u16* __restrict__ x1h16, const u16* __restrict__ x1l16,
                                           const u16* __restrict__ x1T, char* LDS, int bufoff,
                                           long bN, long vtb, int kt, int wid, int lane) {
  int l16 = lane * 16;
#pragma unroll
  for (int i = 0; i < 16; ++i) {
    int S = wid * 16 + i;
    char* dst = LDS + bufoff + S * 1024;
    if (S < 32) {                                  // wave-uniform branch
      int seg = S & 15;
      int r = seg * 2 + (lane >> 5);
      int p = lane & 31;
      int c = p ^ (r & 7);
      const u16* base = (S < 16) ? x1h16 : x1l16;
      const u16* src = base + ((bN + kt * 32 + r) << 8) + (c << 3);
      gload_lds16(src, dst);
    } else {
      int seg = S - 32;
      int e = seg * 8 + (lane >> 3);
      int c = ((lane & 7) ^ (e & 7)) & 3;          // chunks>=4 duplicate (never read)
      const u16* src = x1T + vtb + ((long)e << 12) + kt * 32 + (c << 3);
      gload_lds16(src, dst);
    }
  }
}

__global__ __launch_bounds__(256, 1) void k_flash(const u16* __restrict__ x1h16,
                                                  const u16* __restrict__ x1l16,
                                                  const u16* __restrict__ x1T,
                                                  const float* __restrict__ inp,
                                                  float* __restrict__ out) {
  extern __shared__ char LDS[];
  int phys = blockIdx.x;
  int logical = (phys & 7) * 32 + (phys >> 3);     // XCD b <-> batch b
  int b = logical >> 5, mt = logical & 31;
  int tid = threadIdx.x, wid = tid >> 6, lane = tid & 63;
  int r31 = lane & 31, hi = lane >> 5;
  const long bN = (long)b << 12;
  const long vtb = (long)b << 20;

  // Q (single f16) in regs: B-frag of S^T=mfma(K,Q): col=lane&31=qrow, k=(lane>>5)*8+j
  const long qrow = bN + mt * 128 + wid * 32 + r31;
  f16x8 qh[16];
#pragma unroll
  for (int ks = 0; ks < 16; ++ks)
    qh[ks] = *reinterpret_cast<const f16x8*>(x1h16 + (qrow << 8) + ks * 16 + hi * 8);

  f32x16 o8[8];
#pragma unroll
  for (int nf = 0; nf < 8; ++nf) o8[nf] = z16();
  float mrow = -1.0e30f, lrow = 0.f;

  stage_tile(x1h16, x1l16, x1T, LDS, 0, bN, vtb, 0, wid, lane);

#pragma unroll 1
  for (int kt = 0; kt < 128; ++kt) {
    int cb = (kt & 1) * 65536;
    if (kt < 127) {
      stage_tile(x1h16, x1l16, x1T, LDS, 65536 - cb, bN, vtb, kt + 1, wid, lane);
      asm volatile("s_waitcnt vmcnt(16)" ::: "memory");   // current tile's 16 done; next 16 in flight
    } else {
      asm volatile("s_waitcnt vmcnt(0)" ::: "memory");
    }
    __builtin_amdgcn_s_barrier();
    __builtin_amdgcn_sched_barrier(0);

    const char* KB = LDS + cb;
    // ---- S^T = Kh.Q + Kl.Q (two parallel accumulation chains) ----
    f32x16 stA = z16(), stB = z16();
    int krow = r31 << 9;
    int kx = (r31 & 7) << 4;
#pragma unroll
    for (int ks = 0; ks < 16; ++ks) {
      int cby = (ks * 32 + hi * 16) ^ kx;
      f16x8 kh = *reinterpret_cast<const f16x8*>(KB + krow + cby);
      f16x8 kl = *reinterpret_cast<const f16x8*>(KB + 16384 + krow + cby);
      stA = __builtin_amdgcn_mfma_f32_32x32x16_f16(kh, qh[ks], stA, 0, 0, 0);
      stB = __builtin_amdgcn_mfma_f32_32x32x16_f16(kl, qh[ks], stB, 0, 0, 0);
    }
    f32x16 st;
#pragma unroll
    for (int m = 0; m < 16; ++m) st[m] = stA[m] + stB[m];

    // ---- online softmax; lane holds qrow=lane&31, kv rows (m&3)+8*(m>>2)+4*hi ----
    float tmax = st[0];
#pragma unroll
    for (int m = 1; m < 16; ++m) tmax = fmaxf(tmax, st[m]);
    tmax = fmaxf(tmax, __shfl_xor(tmax, 32));
    if (!__all(tmax <= mrow + 8.0f)) {             // defer-max (T13)
      float mnew = fmaxf(mrow, tmax);
      float alpha = __expf(mrow - mnew);
      lrow *= alpha;
      float ar[16];
#pragma unroll
      for (int m = 0; m < 16; ++m) ar[m] = __shfl(alpha, (m & 3) + 8 * (m >> 2) + 4 * hi);
#pragma unroll
      for (int nf = 0; nf < 8; ++nf)
#pragma unroll
        for (int m = 0; m < 16; ++m) o8[nf][m] *= ar[m];
      mrow = mnew;
    }
    float psum = 0.f;
#pragma unroll
    for (int m = 0; m < 16; ++m) { float p = __expf(st[m] - mrow); st[m] = p; psum += p; }
    psum += __shfl_xor(psum, 32);
    lrow += psum;

    // ---- P -> f16 words; re-fragment via shfl_xor(32) (no LDS) ----
    int W[8], X[8];
#pragma unroll
    for (int m = 0; m < 8; ++m) {
      unsigned lo = __builtin_bit_cast(u16, (_Float16)st[2 * m]);
      unsigned hi2 = __builtin_bit_cast(u16, (_Float16)st[2 * m + 1]);
      W[m] = (int)(lo | (hi2 << 16));
    }
#pragma unroll
    for (int m = 0; m < 8; ++m) X[m] = __shfl_xor(W[m], 32);
    union PU { int w[4]; f16x8 v; };
    PU p0, p1;
    p0.w[0] = hi ? X[2] : W[0]; p0.w[1] = hi ? X[3] : W[1];
    p0.w[2] = hi ? W[2] : X[0]; p0.w[3] = hi ? W[3] : X[1];
    p1.w[0] = hi ? X[6] : W[4]; p1.w[1] = hi ? X[7] : W[5];
    p1.w[2] = hi ? W[6] : X[4]; p1.w[3] = hi ? W[7] : X[5];

    // ---- O += P.V ----
#pragma unroll
    for (int nf = 0; nf < 8; ++nf) {
      int e = nf * 32 + r31;
      int rowo = 32768 + (e << 7);
      int ex = (e & 7) << 4;
      f16x8 v0 = *reinterpret_cast<const f16x8*>(KB + rowo + ((hi * 16) ^ ex));
      f16x8 v1 = *reinterpret_cast<const f16x8*>(KB + rowo + ((32 + hi * 16) ^ ex));
      o8[nf] = __builtin_amdgcn_mfma_f32_32x32x16_f16(p0.v, v0, o8[nf], 0, 0, 0);
      o8[nf] = __builtin_amdgcn_mfma_f32_32x32x16_f16(p1.v, v1, o8[nf], 0, 0, 0);
    }
    __builtin_amdgcn_s_barrier();
  }

  // ---- epilogue: /(16*l) * inp ----
  float linv = 1.0f / (16.0f * lrow);
  float lr[16];
#pragma unroll
  for (int m = 0; m < 16; ++m) lr[m] = __shfl(linv, (m & 3) + 8 * (m >> 2) + 4 * hi);
  const long ob = (bN + mt * 128 + wid * 32) << 8;
#pragma unroll
  for (int nf = 0; nf < 8; ++nf)
#pragma unroll
    for (int m = 0; m < 16; ++m) {
      int qr = (m & 3) + 8 * (m >> 2) + 4 * hi;
      long off = ob + ((long)qr << 8) + nf * 32 + r31;
      out[off] = o8[nf][m] * lr[m] * inp[off];
    }
}

// ---------------- host ----------------
extern "C" void kernel_launch(void* const* d_in, const int* in_sizes, int n_in,
                              void* d_out, int out_size, void* d_ws, size_t ws_size,
                              hipStream_t stream) {
  const float* inp   = (const float*)d_in[0];
  const float* convw = (const float*)d_in[1];
  const float* convb = (const float*)d_in[2];
  float* out = (float*)d_out;
  char* ws = (char*)d_ws;

  u16* x1h   = (u16*)(ws);                 // f16 hi
  u16* x1l   = (u16*)(ws + 16777216L);     // f16 lo
  u16* x1T   = (u16*)(ws + 33554432L);     // f16 hi, transposed
  u16* in_hi = (u16*)(ws + 50331648L);     // bf16 (conv)
  u16* in_lo = (u16*)(ws + 67108864L);
  u16* whT   = (u16*)(ws + 83886080L);
  u16* wlT   = (u16*)(ws + 83886080L + 1179648L);

  (void)hipFuncSetAttribute((const void*)k_flash,
                            hipFuncAttributeMaxDynamicSharedMemorySize, 131072);

  k_split<<<8192, 256, 0, stream>>>(inp, in_hi, in_lo, 2097152);
  k_wsplit<<<2304, 256, 0, stream>>>(convw, whT, wlT);
  k_conv<<<512, 256, 0, stream>>>(in_hi, in_lo, whT, wlT, convb, x1h, x1l);
  k_trans<<<2048, 256, 0, stream>>>(x1h, x1T);
  k_flash<<<256, 256, 131072, stream>>>(x1h, x1l, x1T, inp, out);
}

// Round 4
// 459.650 us; speedup vs baseline: 1.2385x; 1.2385x over previous
//
#include <hip/hip_runtime.h>
#include <hip/hip_bf16.h>

typedef __attribute__((ext_vector_type(8))) short bf16x8;   // 8 bf16 (conv)
typedef __attribute__((ext_vector_type(4))) float f32x4;
typedef __attribute__((ext_vector_type(8))) _Float16 f16x8; // MFMA f16 A/B frag
typedef __attribute__((ext_vector_type(16))) float f32x16;  // 32x32 MFMA C/D
typedef __hip_bfloat16 bf16;
typedef unsigned short u16;

#define NB 8
#define NE 256
#define NN 4096
#define SD 64

__device__ __forceinline__ u16 f2b_bits(float x) {
  bf16 h = __float2bfloat16(x);
  return *reinterpret_cast<u16*>(&h);
}
__device__ __forceinline__ f32x16 z16() {
  f32x16 v;
#pragma unroll
  for (int i = 0; i < 16; ++i) v[i] = 0.f;
  return v;
}
__device__ __forceinline__ void gload_lds16(const void* g, void* l) {
  __builtin_amdgcn_global_load_lds((const __attribute__((address_space(1))) void*)g,
                                   (__attribute__((address_space(3))) void*)l, 16, 0, 0);
}

// lane-half swap: a' = {a_lo, b_lo}, b' = {a_hi, b_hi} (T12)
#if __has_builtin(__builtin_amdgcn_permlane32_swap)
typedef int i32x2 __attribute__((ext_vector_type(2)));
__device__ __forceinline__ void plswap(int& a, int& b) {
  i32x2 r = __builtin_amdgcn_permlane32_swap(a, b, false, false);
  a = r[0]; b = r[1];
}
#else
__device__ __forceinline__ void plswap(int& a, int& b) {
  int xa = __shfl_xor(a, 32), xb = __shfl_xor(b, 32);
  int hi = (int)((threadIdx.x & 63) >> 5);
  int na = hi ? xb : a;
  int nb = hi ? b : xa;
  a = na; b = nb;
}
#endif

// ---------------- split f32 -> bf16 hi/lo (conv inputs) ----------------
__global__ __launch_bounds__(256) void k_split(const float* __restrict__ x,
                                               u16* __restrict__ hi, u16* __restrict__ lo, int n4) {
  int i = blockIdx.x * 256 + threadIdx.x;
  if (i >= n4) return;
  float4 v = reinterpret_cast<const float4*>(x)[i];
  float f[4] = {v.x, v.y, v.z, v.w};
  u16 hh[4], ll[4];
#pragma unroll
  for (int j = 0; j < 4; ++j) {
    bf16 hb = __float2bfloat16(f[j]);
    float hf = __bfloat162float(hb);
    hh[j] = *reinterpret_cast<u16*>(&hb);
    ll[j] = f2b_bits(f[j] - hf);
  }
  reinterpret_cast<ushort4*>(hi)[i] = make_ushort4(hh[0], hh[1], hh[2], hh[3]);
  reinterpret_cast<ushort4*>(lo)[i] = make_ushort4(ll[0], ll[1], ll[2], ll[3]);
}

// ------- split + transpose conv weights: w[t][ei][eo] -> whT[t][eo][ei] -------
__global__ __launch_bounds__(256) void k_wsplit(const float* __restrict__ w,
                                                u16* __restrict__ whT, u16* __restrict__ wlT) {
  int i = blockIdx.x * 256 + threadIdx.x;
  int t = i >> 16;
  int r = i & 65535;
  int ei = r >> 8, eo = r & 255;
  float x = w[i];
  bf16 hb = __float2bfloat16(x);
  float hf = __bfloat162float(hb);
  int o = (t << 16) + (eo << 8) + ei;
  whT[o] = *reinterpret_cast<u16*>(&hb);
  wlT[o] = f2b_bits(x - hf);
}

// ---------------- conv 3x3 implicit GEMM, split-bf16; epilogue -> f16 ----------------
__global__ __launch_bounds__(256) void k_conv(const u16* __restrict__ inh, const u16* __restrict__ inl,
                                              const u16* __restrict__ whT, const u16* __restrict__ wlT,
                                              const float* __restrict__ bias,
                                              u16* __restrict__ x1h) {
  __shared__ u16 Ah[128][72], Al[128][72];
  __shared__ u16 Bh[128][72], Bl[128][72];
  int b = blockIdx.x >> 6;
  int rem = blockIdx.x & 63;
  int mt = rem >> 1, et = rem & 1;
  int h0 = mt << 1;
  int tid = threadIdx.x;
  int wid = tid >> 6, lane = tid & 63;
  int wr = wid >> 1, wc = wid & 1;
  int r = lane & 15, g = lane >> 4;
  f32x4 acc[4][4];
#pragma unroll
  for (int i = 0; i < 4; ++i)
#pragma unroll
    for (int j = 0; j < 4; ++j) acc[i][j] = (f32x4){0.f, 0.f, 0.f, 0.f};
  const long ibase = (long)b * NN * NE;

#pragma unroll 1
  for (int t = 0; t < 9; ++t) {
    int dy = t / 3 - 1, dx = t % 3 - 1;
#pragma unroll 1
    for (int kc = 0; kc < 4; ++kc) {
      __syncthreads();
      for (int c = tid; c < 1024; c += 256) {
        int pix = c >> 3, c8 = c & 7;
        int ww = pix & 63, hh = h0 + (pix >> 6);
        int sh = hh + dy, sw = ww + dx;
        float4 vh = make_float4(0.f, 0.f, 0.f, 0.f), vl = vh;
        if ((unsigned)sh < 64u && (unsigned)sw < 64u) {
          long off = ibase + ((long)sh * 64 + sw) * NE + kc * 64 + c8 * 8;
          vh = *reinterpret_cast<const float4*>(inh + off);
          vl = *reinterpret_cast<const float4*>(inl + off);
        }
        *reinterpret_cast<float4*>(&Ah[pix][c8 * 8]) = vh;
        *reinterpret_cast<float4*>(&Al[pix][c8 * 8]) = vl;
      }
      for (int c = tid; c < 1024; c += 256) {
        int eo = c >> 3, c8 = c & 7;
        long off = ((long)t << 16) + (et * 128 + eo) * 256 + kc * 64 + c8 * 8;
        *reinterpret_cast<float4*>(&Bh[eo][c8 * 8]) = *reinterpret_cast<const float4*>(whT + off);
        *reinterpret_cast<float4*>(&Bl[eo][c8 * 8]) = *reinterpret_cast<const float4*>(wlT + off);
      }
      __syncthreads();
#pragma unroll
      for (int ks = 0; ks < 2; ++ks) {
        int c8 = ks * 4 + g;
        bf16x8 ah[4], al[4], bh[4], bl[4];
#pragma unroll
        for (int mi = 0; mi < 4; ++mi) {
          int row = wr * 64 + mi * 16 + r;
          ah[mi] = *reinterpret_cast<const bf16x8*>(&Ah[row][c8 * 8]);
          al[mi] = *reinterpret_cast<const bf16x8*>(&Al[row][c8 * 8]);
        }
#pragma unroll
        for (int ni = 0; ni < 4; ++ni) {
          int col = wc * 64 + ni * 16 + r;
          bh[ni] = *reinterpret_cast<const bf16x8*>(&Bh[col][c8 * 8]);
          bl[ni] = *reinterpret_cast<const bf16x8*>(&Bl[col][c8 * 8]);
        }
#pragma unroll
        for (int mi = 0; mi < 4; ++mi)
#pragma unroll
          for (int ni = 0; ni < 4; ++ni) {
            acc[mi][ni] = __builtin_amdgcn_mfma_f32_16x16x32_bf16(ah[mi], bh[ni], acc[mi][ni], 0, 0, 0);
            acc[mi][ni] = __builtin_amdgcn_mfma_f32_16x16x32_bf16(ah[mi], bl[ni], acc[mi][ni], 0, 0, 0);
            acc[mi][ni] = __builtin_amdgcn_mfma_f32_16x16x32_bf16(al[mi], bh[ni], acc[mi][ni], 0, 0, 0);
          }
      }
    }
  }
#pragma unroll
  for (int mi = 0; mi < 4; ++mi)
#pragma unroll
    for (int ni = 0; ni < 4; ++ni) {
      int eo = et * 128 + wc * 64 + ni * 16 + r;
      float bz = bias[eo];
#pragma unroll
      for (int i = 0; i < 4; ++i) {
        int pix = mt * 128 + wr * 64 + mi * 16 + g * 4 + i;
        float v = acc[mi][ni][i] + bz;
        long o = ibase + (long)pix * NE + eo;
        x1h[o] = __builtin_bit_cast(u16, (_Float16)v);
      }
    }
}

// ---------------- transpose x1h[b][m][e] -> x1T[b][e][m] ----------------
__global__ __launch_bounds__(256) void k_trans(const u16* __restrict__ x1h, u16* __restrict__ x1T) {
  __shared__ u16 T[64][72];
  int bid = blockIdx.x;
  int b = bid >> 8, rem = bid & 255;
  int mt = rem >> 2, et = rem & 3;
  int tid = threadIdx.x;
  for (int c = tid; c < 512; c += 256) {
    int rr = c >> 3, c8 = c & 7;
    *reinterpret_cast<float4*>(&T[rr][c8 * 8]) =
        *reinterpret_cast<const float4*>(x1h + ((long)b * NN + mt * 64 + rr) * NE + et * 64 + c8 * 8);
  }
  __syncthreads();
  for (int c = tid; c < 512; c += 256) {
    int er = c >> 3, m8 = c & 7;
    union { u16 u[8]; float4 v; } p;
#pragma unroll
    for (int j = 0; j < 8; ++j) p.u[j] = T[m8 * 8 + j][er];
    *reinterpret_cast<float4*>(x1T + ((long)b * NE + et * 64 + er) * NN + mt * 64 + m8 * 8) = p.v;
  }
}

// ---------------- fused flash attention, f16, 32x32 MFMA, KVBLK=64 ----------------
// block 256 = 4 waves, wave owns 32 q-rows; grid 256 (8b x 32mt, XCD-swizzled).
// LDS/buf 64KB: K[64 rows][512B] @0 (XOR swz (r&7)<<4), Vt[256 rows][128B] @32K
// (XOR swz (e&7)<<4); 2 buffers = 128KB. Staged via global_load_lds, source pre-swizzled.
__device__ __forceinline__ void stage_tile(const u16* __restrict__ x1h16, const u16* __restrict__ x1T,
                                           char* LDS, int bufoff, long bN, long vtb,
                                           int kt, int wid, int lane) {
#pragma unroll
  for (int i = 0; i < 16; ++i) {
    int S = wid * 16 + i;                       // 64 segs of 1KB
    char* dst = LDS + bufoff + S * 1024;        // HW adds lane*16
    if (S < 32) {                               // K: 2 rows (512B) per seg
      int r = 2 * S + (lane >> 5);
      int c = (((lane & 31) << 4) ^ ((r & 7) << 4));
      const u16* src = x1h16 + ((bN + kt * 64 + r) << 8) + (c >> 1);
      gload_lds16(src, dst);
    } else {                                    // V: 8 e-rows (128B) per seg
      int e = (S - 32) * 8 + (lane >> 3);
      int c = (((lane & 7) << 4) ^ ((e & 7) << 4));
      const u16* src = x1T + vtb + ((long)e << 12) + kt * 64 + (c >> 1);
      gload_lds16(src, dst);
    }
  }
}

__global__ __launch_bounds__(256, 1) void k_flash(const u16* __restrict__ x1h16,
                                                  const u16* __restrict__ x1T,
                                                  const float* __restrict__ inp,
                                                  float* __restrict__ out) {
  extern __shared__ char LDS[];
  int phys = blockIdx.x;
  int logical = (phys & 7) * 32 + (phys >> 3);  // XCD k <-> batch k (K/V L2-resident)
  int b = logical >> 5, mt = logical & 31;
  int tid = threadIdx.x, wid = tid >> 6, lane = tid & 63;
  int r31 = lane & 31, hi = lane >> 5;
  const long bN = (long)b << 12;
  const long vtb = (long)b << 20;

  // Q (f16) in regs: B-frag of S^T=mfma(K,Q): col=lane&31=qrow, k=hi*8+j
  const long qrow = bN + mt * 128 + wid * 32 + r31;
  f16x8 qh[16];
#pragma unroll
  for (int ks = 0; ks < 16; ++ks)
    qh[ks] = *reinterpret_cast<const f16x8*>(x1h16 + (qrow << 8) + ks * 16 + hi * 8);

  f32x16 o8[8];
#pragma unroll
  for (int nf = 0; nf < 8; ++nf) o8[nf] = z16();
  float mrow = -1.0e30f, lrow = 0.f;

  stage_tile(x1h16, x1T, LDS, 0, bN, vtb, 0, wid, lane);

#pragma unroll 1
  for (int kt = 0; kt < 64; ++kt) {
    int cb = (kt & 1) * 65536;
    if (kt < 63) {
      stage_tile(x1h16, x1T, LDS, 65536 - cb, bN, vtb, kt + 1, wid, lane);
      asm volatile("s_waitcnt vmcnt(16)" ::: "memory");  // current tile's 16 done; next 16 in flight
    } else {
      asm volatile("s_waitcnt vmcnt(0)" ::: "memory");
    }
    __builtin_amdgcn_s_barrier();
    __builtin_amdgcn_sched_barrier(0);

    const char* KB = LDS + cb;
    const char* VB = KB + 32768;

    // ---- S^T = K.Q : two 32x32 tiles (kv halves) ----
    f32x16 st0 = z16(), st1 = z16();
    int swzk = (r31 & 7) << 4;
    int krow0 = r31 << 9, krow1 = (32 + r31) << 9;
#pragma unroll
    for (int ks = 0; ks < 16; ++ks) {
      int cby = (ks * 32 + hi * 16) ^ swzk;
      f16x8 k0 = *reinterpret_cast<const f16x8*>(KB + krow0 + cby);
      f16x8 k1 = *reinterpret_cast<const f16x8*>(KB + krow1 + cby);
      st0 = __builtin_amdgcn_mfma_f32_32x32x16_f16(k0, qh[ks], st0, 0, 0, 0);
      st1 = __builtin_amdgcn_mfma_f32_32x32x16_f16(k1, qh[ks], st1, 0, 0, 0);
    }

    // ---- online softmax (qrow = lane&31; kv = (m&3)+8*(m>>2)+4*hi [+32 for st1]) ----
    float tmax = st0[0];
#pragma unroll
    for (int m = 1; m < 16; ++m) tmax = fmaxf(tmax, st0[m]);
#pragma unroll
    for (int m = 0; m < 16; ++m) tmax = fmaxf(tmax, st1[m]);
    tmax = fmaxf(tmax, __shfl_xor(tmax, 32));
    if (!__all(tmax <= mrow + 8.0f)) {          // defer-max (T13)
      float mnew = fmaxf(mrow, tmax);
      float alpha = __expf(mrow - mnew);
      lrow *= alpha;
      float ar[16];
#pragma unroll
      for (int m = 0; m < 16; ++m) ar[m] = __shfl(alpha, (m & 3) + 8 * (m >> 2) + 4 * hi);
#pragma unroll
      for (int nf = 0; nf < 8; ++nf)
#pragma unroll
        for (int m = 0; m < 16; ++m) o8[nf][m] *= ar[m];
      mrow = mnew;
    }
    float psum = 0.f;
#pragma unroll
    for (int m = 0; m < 16; ++m) { float p = __expf(st0[m] - mrow); st0[m] = p; psum += p; }
#pragma unroll
    for (int m = 0; m < 16; ++m) { float p = __expf(st1[m] - mrow); st1[m] = p; psum += p; }
    psum += __shfl_xor(psum, 32);
    lrow += psum;

    // ---- P -> f16, re-fragment via permlane32_swap: 4 A-frags (kv chunks of 16) ----
    int Wd[16];
#pragma unroll
    for (int m = 0; m < 8; ++m) {
      unsigned l0 = __builtin_bit_cast(u16, (_Float16)st0[2 * m]);
      unsigned h0 = __builtin_bit_cast(u16, (_Float16)st0[2 * m + 1]);
      Wd[m] = (int)(l0 | (h0 << 16));
      unsigned l1 = __builtin_bit_cast(u16, (_Float16)st1[2 * m]);
      unsigned h1 = __builtin_bit_cast(u16, (_Float16)st1[2 * m + 1]);
      Wd[8 + m] = (int)(l1 | (h1 << 16));
    }
    plswap(Wd[0], Wd[2]);  plswap(Wd[1], Wd[3]);
    plswap(Wd[4], Wd[6]);  plswap(Wd[5], Wd[7]);
    plswap(Wd[8], Wd[10]); plswap(Wd[9], Wd[11]);
    plswap(Wd[12], Wd[14]); plswap(Wd[13], Wd[15]);
    union PU { int w[4]; f16x8 v; };
    PU pa[4];
#pragma unroll
    for (int c = 0; c < 4; ++c) {
      pa[c].w[0] = Wd[c * 4 + 0]; pa[c].w[1] = Wd[c * 4 + 1];
      pa[c].w[2] = Wd[c * 4 + 2]; pa[c].w[3] = Wd[c * 4 + 3];
    }

    // ---- O += P.V ----
#pragma unroll
    for (int nf = 0; nf < 8; ++nf) {
      int e = nf * 32 + r31;
      const char* vrow = VB + (e << 7);
      int swzv = (e & 7) << 4;
#pragma unroll
      for (int c = 0; c < 4; ++c) {
        f16x8 v = *reinterpret_cast<const f16x8*>(vrow + ((c * 32 + hi * 16) ^ swzv));
        o8[nf] = __builtin_amdgcn_mfma_f32_32x32x16_f16(pa[c].v, v, o8[nf], 0, 0, 0);
      }
    }
    __builtin_amdgcn_s_barrier();
  }

  // ---- epilogue: /(16*l) * inp ----
  float linv = 1.0f / (16.0f * lrow);
  float lr[16];
#pragma unroll
  for (int m = 0; m < 16; ++m) lr[m] = __shfl(linv, (m & 3) + 8 * (m >> 2) + 4 * hi);
  const long ob = (bN + mt * 128 + wid * 32) << 8;
#pragma unroll
  for (int nf = 0; nf < 8; ++nf)
#pragma unroll
    for (int m = 0; m < 16; ++m) {
      int qr = (m & 3) + 8 * (m >> 2) + 4 * hi;
      long off = ob + ((long)qr << 8) + nf * 32 + r31;
      out[off] = o8[nf][m] * lr[m] * inp[off];
    }
}

// ---------------- host ----------------
extern "C" void kernel_launch(void* const* d_in, const int* in_sizes, int n_in,
                              void* d_out, int out_size, void* d_ws, size_t ws_size,
                              hipStream_t stream) {
  const float* inp   = (const float*)d_in[0];
  const float* convw = (const float*)d_in[1];
  const float* convb = (const float*)d_in[2];
  float* out = (float*)d_out;
  char* ws = (char*)d_ws;

  u16* x1h   = (u16*)(ws);                 // f16
  u16* x1T   = (u16*)(ws + 16777216L);     // f16, transposed
  u16* in_hi = (u16*)(ws + 33554432L);     // bf16 (conv input split)
  u16* in_lo = (u16*)(ws + 50331648L);
  u16* whT   = (u16*)(ws + 67108864L);
  u16* wlT   = (u16*)(ws + 67108864L + 1179648L);

  (void)hipFuncSetAttribute((const void*)k_flash,
                            hipFuncAttributeMaxDynamicSharedMemorySize, 131072);

  k_split<<<8192, 256, 0, stream>>>(inp, in_hi, in_lo, 2097152);
  k_wsplit<<<2304, 256, 0, stream>>>(convw, whT, wlT);
  k_conv<<<512, 256, 0, stream>>>(in_hi, in_lo, whT, wlT, convb, x1h);
  k_trans<<<2048, 256, 0, stream>>>(x1h, x1T);
  k_flash<<<256, 256, 131072, stream>>>(x1h, x1T, inp, out);
}